// Round 1
// baseline (1756.817 us; speedup 1.0000x reference)
//
#include <hip/hip_runtime.h>
#include <hip/hip_bf16.h>

#define NB 8
#define NP 8192
#define IMH 512
#define IMW 512
#define NC 192
#define FH 128
#define FW 128
#define NSTATE 256

typedef __attribute__((ext_vector_type(8))) unsigned short ush8;

__device__ __forceinline__ float bf2f(unsigned short u) {
  return __uint_as_float(((unsigned)u) << 16);
}

// ---------------- conv 4x4 stride4: NCHW f32 -> NHWC bf16 ----------------
__global__ void conv_kernel(const float* __restrict__ img,
                            const float* __restrict__ bw,
                            const float* __restrict__ bb,
                            __hip_bfloat16* __restrict__ feat) {
  int idx = blockIdx.x * 256 + threadIdx.x;  // ((b*FH+y)*FW+x)*NC + c
  int c = idx % NC;
  int t = idx / NC;
  int x = t % FW; t /= FW;
  int y = t % FH; t /= FH;
  int b = t;
  const float* wr = bw + c * 48;
  const float* ip = img + (size_t)b * 3 * IMH * IMW;
  float acc = bb[c];
#pragma unroll
  for (int ci = 0; ci < 3; ++ci) {
#pragma unroll
    for (int ky = 0; ky < 4; ++ky) {
      float4 iv = *(const float4*)(ip + ((size_t)ci * IMH + (y * 4 + ky)) * IMW + x * 4);
      float4 wv = *(const float4*)(wr + (ci * 4 + ky) * 4);
      acc += iv.x * wv.x + iv.y * wv.y + iv.z * wv.z + iv.w * wv.w;
    }
  }
  feat[idx] = __float2bfloat16(acc);
}

// ---------------- per-batch masked min of points ----------------
__global__ void mins_kernel(const float* __restrict__ py,
                            const float* __restrict__ mask,
                            float* __restrict__ mins) {
  int b = blockIdx.x;
  float mx = 1e9f, my = 1e9f;
  for (int n = threadIdx.x; n < NP; n += 256) {
    float m = mask[(size_t)b * NP + n];
    float2 p = *(const float2*)&py[((size_t)b * NP + n) * 2];
    mx = fminf(mx, m > 0.0f ? p.x : 1e9f);
    my = fminf(my, m > 0.0f ? p.y : 1e9f);
  }
#pragma unroll
  for (int o = 32; o > 0; o >>= 1) {
    mx = fminf(mx, __shfl_down(mx, o));
    my = fminf(my, __shfl_down(my, o));
  }
  __shared__ float sx[4], sy[4];
  if ((threadIdx.x & 63) == 0) { sx[threadIdx.x >> 6] = mx; sy[threadIdx.x >> 6] = my; }
  __syncthreads();
  if (threadIdx.x == 0) {
    mx = fminf(fminf(sx[0], sx[1]), fminf(sx[2], sx[3]));
    my = fminf(fminf(sy[0], sy[1]), fminf(sy[2], sy[3]));
    mins[b * 2 + 0] = mx;
    mins[b * 2 + 1] = my;
  }
}

// FMA micro-step: A row broadcast x B row chunk into 4x16 accumulator
#define FMA_STEP(ACC, KROW, KK)                                              \
  {                                                                          \
    const float4 av = *(const float4*)&Als[(KROW) * 64 + ty * 4];            \
    const float* bp = &Bls[(KK) * 256 + tx * 16];                            \
    const float4 bv0 = *(const float4*)(bp + 0);                             \
    const float4 bv1 = *(const float4*)(bp + 4);                             \
    const float4 bv2 = *(const float4*)(bp + 8);                             \
    const float4 bv3 = *(const float4*)(bp + 12);                            \
    const float aa[4] = {av.x, av.y, av.z, av.w};                            \
    const float bbv[16] = {bv0.x, bv0.y, bv0.z, bv0.w, bv1.x, bv1.y, bv1.z,  \
                           bv1.w, bv2.x, bv2.y, bv2.z, bv2.w, bv3.x, bv3.y,  \
                           bv3.z, bv3.w};                                    \
    _Pragma("unroll") for (int mi_ = 0; mi_ < 4; ++mi_)                      \
        _Pragma("unroll") for (int ni_ = 0; ni_ < 16; ++ni_)                 \
            ACC[mi_][ni_] = fmaf(aa[mi_], bbv[ni_], ACC[mi_][ni_]);          \
  }

// ---------------- fused gather + 3-layer MLP (+ epilogue) ----------------
// !CLS: x=[g(192), canon(2)]; out0 = p_out (py + off*4)
//  CLS: x=[g(192), py(2), angle(1)]; out0 = d_out (points*4 then cls)
template <bool CLS>
__global__ __launch_bounds__(256, 2) void mlp_kernel(
    const __hip_bfloat16* __restrict__ feat,
    const float* __restrict__ p_in,
    const float* __restrict__ mask,
    const float* __restrict__ mins,
    const float* __restrict__ W1, const float* __restrict__ b1,
    const float* __restrict__ W2, const float* __restrict__ b2,
    const float* __restrict__ W3, const float* __restrict__ b3,
    float* __restrict__ out0) {
  constexpr int KDIM = CLS ? 195 : 194;
  __shared__ float Als[256 * 64];   // A: [k][m]  (X then H1)
  __shared__ float Bls[16 * 256];   // W chunk: [kk][n]

  const int tid = threadIdx.x;
  const int tx = tid & 15;   // owns n in [tx*16, tx*16+16)
  const int ty = tid >> 4;   // owns m in [ty*4, ty*4+4)
  const int blk = blockIdx.x;
  const int b = blk >> 7;            // / (NP/64)
  const int m0 = (blk & 127) * 64;

  // ---- gather phase: build A1 ----
  {
    const int m = tid & 63;
    const int j = tid >> 6;  // channel quarter, contiguous c in [j*48,(j+1)*48)
    const int n = m0 + m;
    const size_t pidx = (size_t)b * NP + n;
    const float msk = mask[pidx];
    const float2 pv = *(const float2*)&p_in[pidx * 2];
    const float px = pv.x, pyv = pv.y;
    const float xs = px * (127.0f / 128.0f);
    const float ys = pyv * (127.0f / 128.0f);
    const float x0f = floorf(xs), y0f = floorf(ys);
    const float fx = xs - x0f, fy = ys - y0f;
    const int x0 = (int)fminf(fmaxf(x0f, 0.0f), 127.0f);
    const int x1 = (int)fminf(fmaxf(x0f + 1.0f, 0.0f), 127.0f);
    const int y0 = (int)fminf(fmaxf(y0f, 0.0f), 127.0f);
    const int y1 = (int)fminf(fmaxf(y0f + 1.0f, 0.0f), 127.0f);
    const float w00 = (1.0f - fy) * (1.0f - fx);
    const float w01 = (1.0f - fy) * fx;
    const float w10 = fy * (1.0f - fx);
    const float w11 = fy * fx;
    const __hip_bfloat16* fb = feat + (size_t)b * FH * FW * NC + j * 48;
    const ush8* r00 = (const ush8*)(fb + ((size_t)y0 * FW + x0) * NC);
    const ush8* r01 = (const ush8*)(fb + ((size_t)y0 * FW + x1) * NC);
    const ush8* r10 = (const ush8*)(fb + ((size_t)y1 * FW + x0) * NC);
    const ush8* r11 = (const ush8*)(fb + ((size_t)y1 * FW + x1) * NC);
#pragma unroll
    for (int v = 0; v < 6; ++v) {
      ush8 a0 = r00[v], a1 = r01[v], a2 = r10[v], a3 = r11[v];
#pragma unroll
      for (int e = 0; e < 8; ++e) {
        float g = w00 * bf2f(a0[e]) + w01 * bf2f(a1[e]) +
                  w10 * bf2f(a2[e]) + w11 * bf2f(a3[e]);
        Als[(j * 48 + v * 8 + e) * 64 + m] = g * msk;
      }
    }
    if (j == 0) {
      if constexpr (!CLS) {
        Als[192 * 64 + m] = (px - mins[b * 2 + 0]) * msk;
        Als[193 * 64 + m] = (pyv - mins[b * 2 + 1]) * msk;
      } else {
        Als[192 * 64 + m] = px;
        Als[193 * 64 + m] = pyv;
        const int npv = (n + NP - 1) & (NP - 1);
        const int nnx = (n + 1) & (NP - 1);
        const float2 pp = *(const float2*)&p_in[((size_t)b * NP + npv) * 2];
        const float2 pn = *(const float2*)&p_in[((size_t)b * NP + nnx) * 2];
        const float v1x = pp.x - px, v1y = pp.y - pyv;
        const float v2x = pn.x - px, v2y = pn.y - pyv;
        const float dot = v1x * v2x + v1y * v2y;
        const float nrm =
            sqrtf(v1x * v1x + v1y * v1y) * sqrtf(v2x * v2x + v2y * v2y);
        const float ca = fminf(fmaxf(dot / (nrm + 1e-8f), -1.0f), 1.0f);
        Als[194 * 64 + m] = acosf(ca) * msk;
      }
    }
  }

  // ---- GEMM1: H1 = relu(X @ W1^T + b1) ----
  float acc[4][16];
#pragma unroll
  for (int mi = 0; mi < 4; ++mi)
#pragma unroll
    for (int ni = 0; ni < 16; ++ni) acc[mi][ni] = 0.0f;

  {
    const float* wr = W1 + (size_t)tid * KDIM;
    int k0 = 0;
    for (; k0 + 16 <= KDIM; k0 += 16) {
#pragma unroll
      for (int kk = 0; kk < 16; ++kk) Bls[kk * 256 + tid] = wr[k0 + kk];
      __syncthreads();
#pragma unroll
      for (int kk = 0; kk < 16; ++kk) FMA_STEP(acc, k0 + kk, kk);
      __syncthreads();
    }
    const int kc = KDIM - k0;  // 2 (off) or 3 (cls)
    for (int kk = 0; kk < kc; ++kk) Bls[kk * 256 + tid] = wr[k0 + kk];
    __syncthreads();
    for (int kk = 0; kk < kc; ++kk) FMA_STEP(acc, k0 + kk, kk);
    __syncthreads();
  }

  // write H1 (relu+bias) as A2[k=n][m]
#pragma unroll
  for (int ni = 0; ni < 16; ++ni) {
    const float bias = b1[tx * 16 + ni];
    float4 hv;
    hv.x = fmaxf(acc[0][ni] + bias, 0.0f);
    hv.y = fmaxf(acc[1][ni] + bias, 0.0f);
    hv.z = fmaxf(acc[2][ni] + bias, 0.0f);
    hv.w = fmaxf(acc[3][ni] + bias, 0.0f);
    *(float4*)&Als[(tx * 16 + ni) * 64 + ty * 4] = hv;
  }

  // ---- GEMM2: H2 = relu(H1 @ W2^T + b2) ----
  float acc2[4][16];
#pragma unroll
  for (int mi = 0; mi < 4; ++mi)
#pragma unroll
    for (int ni = 0; ni < 16; ++ni) acc2[mi][ni] = 0.0f;

  {
    const float* wr2 = W2 + (size_t)tid * 256;
    for (int k0 = 0; k0 < 256; k0 += 16) {
#pragma unroll
      for (int kk = 0; kk < 16; ++kk) Bls[kk * 256 + tid] = wr2[k0 + kk];
      __syncthreads();
#pragma unroll
      for (int kk = 0; kk < 16; ++kk) FMA_STEP(acc2, k0 + kk, kk);
      __syncthreads();
    }
  }

  // ---- GEMM3 + epilogue ----
  float pr0[4] = {0, 0, 0, 0};
  float pr1[4] = {0, 0, 0, 0};
  {
    const float* w3a = W3 + tx * 16;
#pragma unroll
    for (int ni = 0; ni < 16; ++ni) {
      const float bias = b2[tx * 16 + ni];
      const float wa = w3a[ni];
      float wb = 0.0f;
      if constexpr (!CLS) wb = w3a[256 + ni];
#pragma unroll
      for (int mi = 0; mi < 4; ++mi) {
        const float t = fmaxf(acc2[mi][ni] + bias, 0.0f);
        pr0[mi] = fmaf(t, wa, pr0[mi]);
        if constexpr (!CLS) pr1[mi] = fmaf(t, wb, pr1[mi]);
      }
    }
  }
#pragma unroll
  for (int s = 1; s < 16; s <<= 1) {
#pragma unroll
    for (int mi = 0; mi < 4; ++mi) {
      pr0[mi] += __shfl_xor(pr0[mi], s);
      if constexpr (!CLS) pr1[mi] += __shfl_xor(pr1[mi], s);
    }
  }
  if (tx == 0) {
#pragma unroll
    for (int mi = 0; mi < 4; ++mi) {
      const int m = ty * 4 + mi;
      const size_t pidx = (size_t)b * NP + m0 + m;
      const float msk = mask[pidx];
      const float2 pv = *(const float2*)&p_in[pidx * 2];
      if constexpr (!CLS) {
        const float ox = (pr0[mi] + b3[0]) * msk;
        const float oy = (pr1[mi] + b3[1]) * msk;
        out0[pidx * 2 + 0] = pv.x + ox * 4.0f;
        out0[pidx * 2 + 1] = pv.y + oy * 4.0f;
      } else {
        out0[pidx * 2 + 0] = pv.x * 4.0f;
        out0[pidx * 2 + 1] = pv.y * 4.0f;
        out0[(size_t)2 * NB * NP + pidx] = (pr0[mi] + b3[0]) * msk;
      }
    }
  }
}

extern "C" void kernel_launch(void* const* d_in, const int* in_sizes, int n_in,
                              void* d_out, int out_size, void* d_ws,
                              size_t ws_size, hipStream_t stream) {
  const float* image = (const float*)d_in[0];
  const float* pred  = (const float*)d_in[1];
  const float* mask  = (const float*)d_in[2];
  const float* bw    = (const float*)d_in[3];
  const float* bb    = (const float*)d_in[4];
  const float* oW1   = (const float*)d_in[5];
  const float* ob1   = (const float*)d_in[6];
  const float* oW2   = (const float*)d_in[7];
  const float* ob2   = (const float*)d_in[8];
  const float* oW3   = (const float*)d_in[9];
  const float* ob3   = (const float*)d_in[10];
  const float* cW1   = (const float*)d_in[11];
  const float* cb1   = (const float*)d_in[12];
  const float* cW2   = (const float*)d_in[13];
  const float* cb2   = (const float*)d_in[14];
  const float* cW3   = (const float*)d_in[15];
  const float* cb3   = (const float*)d_in[16];
  float* out = (float*)d_out;

  char* ws = (char*)d_ws;
  __hip_bfloat16* feat = (__hip_bfloat16*)ws;
  const size_t featB = (size_t)NB * FH * FW * NC * 2;  // 50.3 MB
  float* pyA  = (float*)(ws + featB);
  float* pyB  = pyA + (size_t)NB * NP * 2;
  float* mins = pyB + (size_t)NB * NP * 2;

  conv_kernel<<<dim3((NB * FH * FW * NC) / 256), 256, 0, stream>>>(image, bw,
                                                                   bb, feat);

  const float* cur = pred;
  float* nxt = pyA;
  for (int i = 0; i < 3; ++i) {
    mins_kernel<<<dim3(NB), 256, 0, stream>>>(cur, mask, mins);
    mlp_kernel<false><<<dim3(NB * NP / 64), 256, 0, stream>>>(
        feat, cur, mask, mins,
        oW1 + (size_t)i * NSTATE * 194, ob1 + (size_t)i * NSTATE,
        oW2 + (size_t)i * NSTATE * NSTATE, ob2 + (size_t)i * NSTATE,
        oW3 + (size_t)i * 2 * NSTATE, ob3 + (size_t)i * 2, nxt);
    cur = nxt;
    nxt = (nxt == pyA) ? pyB : pyA;
  }
  mlp_kernel<true><<<dim3(NB * NP / 64), 256, 0, stream>>>(
      feat, cur, mask, nullptr, cW1, cb1, cW2, cb2, cW3, cb3, out);
}

// Round 2
// 1097.651 us; speedup vs baseline: 1.6005x; 1.6005x over previous
//
#include <hip/hip_runtime.h>
#include <hip/hip_bf16.h>

#define NB 8
#define NP 8192
#define IMH 512
#define IMW 512
#define NC 192
#define FH 128
#define FW 128
#define NSTATE 256

typedef __attribute__((ext_vector_type(8))) unsigned short ush8;

__device__ __forceinline__ float bf2f(unsigned short u) {
  return __uint_as_float(((unsigned)u) << 16);
}

// ---------------- conv 4x4 stride4 -> feat layout [g][b][pix][48] bf16 ----
// thread = (pixel, channel-group g of 48). 2304 FMAs/thread, weights via
// wave-uniform s_load, output staged in LDS and written coalesced.
__global__ __launch_bounds__(256) void conv_kernel(
    const float* __restrict__ img, const float* __restrict__ bw,
    const float* __restrict__ bb, __hip_bfloat16* __restrict__ feat) {
  __shared__ __hip_bfloat16 ols[4 * 64 * 48];  // [g][pix][48] = 24 KB

  const int tid = threadIdx.x;
  const int pix = tid & 63;
  const int g = tid >> 6;
  const int p0 = blockIdx.x * 64;
  const int p = p0 + pix;
  const int b = p >> 14;
  const int yy = (p >> 7) & 127;
  const int xx = p & 127;

  // 48 input values (3 ci x 4 ky x 4 kx) into registers, coalesced loads
  float xin[48];
#pragma unroll
  for (int ci = 0; ci < 3; ++ci) {
#pragma unroll
    for (int ky = 0; ky < 4; ++ky) {
      float4 v = *(const float4*)(img + (((size_t)b * 3 + ci) * IMH +
                                         (yy * 4 + ky)) * IMW + xx * 4);
      xin[ci * 16 + ky * 4 + 0] = v.x;
      xin[ci * 16 + ky * 4 + 1] = v.y;
      xin[ci * 16 + ky * 4 + 2] = v.z;
      xin[ci * 16 + ky * 4 + 3] = v.w;
    }
  }

  const int gu = __builtin_amdgcn_readfirstlane(g);  // wave-uniform -> s_load
  for (int cc4 = 0; cc4 < 12; ++cc4) {
    float a[4];
#pragma unroll
    for (int i = 0; i < 4; ++i) a[i] = bb[gu * 48 + cc4 * 4 + i];
#pragma unroll
    for (int k4 = 0; k4 < 12; ++k4) {
#pragma unroll
      for (int i = 0; i < 4; ++i) {
        const float4 wv =
            *(const float4*)(bw + (size_t)(gu * 48 + cc4 * 4 + i) * 48 + k4 * 4);
        a[i] = fmaf(wv.x, xin[k4 * 4 + 0], a[i]);
        a[i] = fmaf(wv.y, xin[k4 * 4 + 1], a[i]);
        a[i] = fmaf(wv.z, xin[k4 * 4 + 2], a[i]);
        a[i] = fmaf(wv.w, xin[k4 * 4 + 3], a[i]);
      }
    }
    __hip_bfloat16 h[4];
#pragma unroll
    for (int i = 0; i < 4; ++i) h[i] = __float2bfloat16(a[i]);
    *(uint2*)&ols[(g * 64 + pix) * 48 + cc4 * 4] = *(const uint2*)h;
  }
  __syncthreads();

  // coalesced copy out: 4 regions of 64 pix x 96 B (contiguous each)
  const int bb_ = p0 >> 14;
  const int pixbase = p0 & 16383;
#pragma unroll
  for (int it = 0; it < 6; ++it) {
    const int chunk = it * 256 + tid;  // 0..1535 ush8
    const int gg = chunk / 384;
    const int off = chunk % 384;
    const ush8 val = ((const ush8*)ols)[chunk];
    __hip_bfloat16* dst =
        feat + ((size_t)(gg * 8 + bb_) * 16384 + pixbase) * 48;
    ((ush8*)dst)[off] = val;
  }
}

// ---------------- weight transpose: src [256][K] -> dst [K][256] ----------
__global__ void transpose_kernel(const float* __restrict__ src,
                                 float* __restrict__ dst, int K) {
  const int idx = blockIdx.x * 256 + threadIdx.x;  // coalesced read
  const int n = idx / K;
  const int k = idx % K;
  dst[k * 256 + n] = src[idx];
}

// ---------------- per-batch masked min of points ----------------
__global__ void mins_kernel(const float* __restrict__ py,
                            const float* __restrict__ mask,
                            float* __restrict__ mins) {
  int b = blockIdx.x;
  float mx = 1e9f, my = 1e9f;
  for (int n = threadIdx.x; n < NP; n += 256) {
    float m = mask[(size_t)b * NP + n];
    float2 p = *(const float2*)&py[((size_t)b * NP + n) * 2];
    mx = fminf(mx, m > 0.0f ? p.x : 1e9f);
    my = fminf(my, m > 0.0f ? p.y : 1e9f);
  }
#pragma unroll
  for (int o = 32; o > 0; o >>= 1) {
    mx = fminf(mx, __shfl_down(mx, o));
    my = fminf(my, __shfl_down(my, o));
  }
  __shared__ float sx[4], sy[4];
  if ((threadIdx.x & 63) == 0) { sx[threadIdx.x >> 6] = mx; sy[threadIdx.x >> 6] = my; }
  __syncthreads();
  if (threadIdx.x == 0) {
    mx = fminf(fminf(sx[0], sx[1]), fminf(sx[2], sx[3]));
    my = fminf(fminf(sy[0], sy[1]), fminf(sy[2], sy[3]));
    mins[b * 2 + 0] = mx;
    mins[b * 2 + 1] = my;
  }
}

// FMA micro-step. B layout: Bls[kk][v][txslot][4] -> lane reads at 16B
// stride (2-way bank alias = free) instead of 64B stride (8-way conflict).
#define FMA_STEP(ACC, KROW, KK)                                              \
  {                                                                          \
    const float4 av = *(const float4*)&Als[(KROW) * 64 + ty * 4];            \
    const float4 bv0 = *(const float4*)&Bls[(KK) * 256 + 0 + tx * 4];        \
    const float4 bv1 = *(const float4*)&Bls[(KK) * 256 + 64 + tx * 4];       \
    const float4 bv2 = *(const float4*)&Bls[(KK) * 256 + 128 + tx * 4];      \
    const float4 bv3 = *(const float4*)&Bls[(KK) * 256 + 192 + tx * 4];      \
    const float aa[4] = {av.x, av.y, av.z, av.w};                            \
    const float bbv[16] = {bv0.x, bv0.y, bv0.z, bv0.w, bv1.x, bv1.y, bv1.z,  \
                           bv1.w, bv2.x, bv2.y, bv2.z, bv2.w, bv3.x, bv3.y,  \
                           bv3.z, bv3.w};                                    \
    _Pragma("unroll") for (int mi_ = 0; mi_ < 4; ++mi_)                      \
        _Pragma("unroll") for (int ni_ = 0; ni_ < 16; ++ni_)                 \
            ACC[mi_][ni_] = fmaf(aa[mi_], bbv[ni_], ACC[mi_][ni_]);          \
  }

// stage one 16-row W chunk (Wt is [K][256], coalesced) into swizzled Bls
#define STAGE_B(WT, K0, NK)                                                  \
  {                                                                          \
    const int dsti = ((tid >> 2) & 3) * 64 + (tid >> 4) * 4 + (tid & 3);     \
    for (int kk = 0; kk < (NK); ++kk)                                        \
      Bls[kk * 256 + dsti] = (WT)[(size_t)((K0) + kk) * 256 + tid];          \
  }

// ---------------- fused gather + 3-layer MLP (+ epilogue) ----------------
template <bool CLS>
__global__ __launch_bounds__(256, 2) void mlp_kernel(
    const __hip_bfloat16* __restrict__ feat,
    const float* __restrict__ p_in,
    const float* __restrict__ mask,
    const float* __restrict__ mins,
    const float* __restrict__ Wt1, const float* __restrict__ b1,
    const float* __restrict__ Wt2, const float* __restrict__ b2,
    const float* __restrict__ W3, const float* __restrict__ b3,
    float* __restrict__ out0) {
  constexpr int KDIM = CLS ? 195 : 194;
  __shared__ float Als[256 * 64];  // A: [k][m]  (X then H1)
  __shared__ float Bls[16 * 256];  // W chunk, swizzled

  const int tid = threadIdx.x;
  const int tx = tid & 15;
  const int ty = tid >> 4;
  const int blk = blockIdx.x;
  const int b = blk >> 7;
  const int m0 = (blk & 127) * 64;

  // ---- gather phase ----
  {
    const int m = tid & 63;
    const int j = tid >> 6;
    const int n = m0 + m;
    const size_t pidx = (size_t)b * NP + n;
    const float msk = mask[pidx];
    const float2 pv = *(const float2*)&p_in[pidx * 2];
    const float px = pv.x, pyv = pv.y;
    const float xs = px * (127.0f / 128.0f);
    const float ys = pyv * (127.0f / 128.0f);
    const float x0f = floorf(xs), y0f = floorf(ys);
    const float fx = xs - x0f, fy = ys - y0f;
    const int x0 = (int)fminf(fmaxf(x0f, 0.0f), 127.0f);
    const int x1 = (int)fminf(fmaxf(x0f + 1.0f, 0.0f), 127.0f);
    const int y0 = (int)fminf(fmaxf(y0f, 0.0f), 127.0f);
    const int y1 = (int)fminf(fmaxf(y0f + 1.0f, 0.0f), 127.0f);
    const float w00 = (1.0f - fy) * (1.0f - fx);
    const float w01 = (1.0f - fy) * fx;
    const float w10 = fy * (1.0f - fx);
    const float w11 = fy * fx;
    const __hip_bfloat16* fb = feat + (size_t)(j * 8 + b) * 16384 * 48;
    const ush8* r00 = (const ush8*)(fb + (size_t)(y0 * FW + x0) * 48);
    const ush8* r01 = (const ush8*)(fb + (size_t)(y0 * FW + x1) * 48);
    const ush8* r10 = (const ush8*)(fb + (size_t)(y1 * FW + x0) * 48);
    const ush8* r11 = (const ush8*)(fb + (size_t)(y1 * FW + x1) * 48);
#pragma unroll
    for (int v = 0; v < 6; ++v) {
      ush8 a0 = r00[v], a1 = r01[v], a2 = r10[v], a3 = r11[v];
#pragma unroll
      for (int e = 0; e < 8; ++e) {
        float gg = w00 * bf2f(a0[e]) + w01 * bf2f(a1[e]) +
                   w10 * bf2f(a2[e]) + w11 * bf2f(a3[e]);
        Als[(j * 48 + v * 8 + e) * 64 + m] = gg * msk;
      }
    }
    if (j == 0) {
      if constexpr (!CLS) {
        Als[192 * 64 + m] = (px - mins[b * 2 + 0]) * msk;
        Als[193 * 64 + m] = (pyv - mins[b * 2 + 1]) * msk;
      } else {
        Als[192 * 64 + m] = px;
        Als[193 * 64 + m] = pyv;
        const int npv = (n + NP - 1) & (NP - 1);
        const int nnx = (n + 1) & (NP - 1);
        const float2 pp = *(const float2*)&p_in[((size_t)b * NP + npv) * 2];
        const float2 pn = *(const float2*)&p_in[((size_t)b * NP + nnx) * 2];
        const float v1x = pp.x - px, v1y = pp.y - pyv;
        const float v2x = pn.x - px, v2y = pn.y - pyv;
        const float dot = v1x * v2x + v1y * v2y;
        const float nrm =
            sqrtf(v1x * v1x + v1y * v1y) * sqrtf(v2x * v2x + v2y * v2y);
        const float ca = fminf(fmaxf(dot / (nrm + 1e-8f), -1.0f), 1.0f);
        Als[194 * 64 + m] = acosf(ca) * msk;
      }
    }
  }

  // ---- GEMM1 ----
  float acc[4][16];
#pragma unroll
  for (int mi = 0; mi < 4; ++mi)
#pragma unroll
    for (int ni = 0; ni < 16; ++ni) acc[mi][ni] = 0.0f;
  {
    int k0 = 0;
    for (; k0 + 16 <= KDIM; k0 += 16) {
      STAGE_B(Wt1, k0, 16);
      __syncthreads();
#pragma unroll
      for (int kk = 0; kk < 16; ++kk) FMA_STEP(acc, k0 + kk, kk);
      __syncthreads();
    }
    const int kc = KDIM - k0;  // 2 or 3
    STAGE_B(Wt1, k0, kc);
    __syncthreads();
    for (int kk = 0; kk < kc; ++kk) FMA_STEP(acc, k0 + kk, kk);
    __syncthreads();
  }

  // write H1 (relu+bias) as A2[k=n][m]
#pragma unroll
  for (int ni = 0; ni < 16; ++ni) {
    const float bias = b1[tx * 16 + ni];
    float4 hv;
    hv.x = fmaxf(acc[0][ni] + bias, 0.0f);
    hv.y = fmaxf(acc[1][ni] + bias, 0.0f);
    hv.z = fmaxf(acc[2][ni] + bias, 0.0f);
    hv.w = fmaxf(acc[3][ni] + bias, 0.0f);
    *(float4*)&Als[(tx * 16 + ni) * 64 + ty * 4] = hv;
  }

  // ---- GEMM2 ----
  float acc2[4][16];
#pragma unroll
  for (int mi = 0; mi < 4; ++mi)
#pragma unroll
    for (int ni = 0; ni < 16; ++ni) acc2[mi][ni] = 0.0f;
  for (int k0 = 0; k0 < 256; k0 += 16) {
    STAGE_B(Wt2, k0, 16);
    __syncthreads();
#pragma unroll
    for (int kk = 0; kk < 16; ++kk) FMA_STEP(acc2, k0 + kk, kk);
    __syncthreads();
  }

  // ---- GEMM3 + epilogue ----
  float pr0[4] = {0, 0, 0, 0};
  float pr1[4] = {0, 0, 0, 0};
  {
    const float* w3a = W3 + tx * 16;
#pragma unroll
    for (int ni = 0; ni < 16; ++ni) {
      const float bias = b2[tx * 16 + ni];
      const float wa = w3a[ni];
      float wb = 0.0f;
      if constexpr (!CLS) wb = w3a[256 + ni];
#pragma unroll
      for (int mi = 0; mi < 4; ++mi) {
        const float t = fmaxf(acc2[mi][ni] + bias, 0.0f);
        pr0[mi] = fmaf(t, wa, pr0[mi]);
        if constexpr (!CLS) pr1[mi] = fmaf(t, wb, pr1[mi]);
      }
    }
  }
#pragma unroll
  for (int s = 1; s < 16; s <<= 1) {
#pragma unroll
    for (int mi = 0; mi < 4; ++mi) {
      pr0[mi] += __shfl_xor(pr0[mi], s);
      if constexpr (!CLS) pr1[mi] += __shfl_xor(pr1[mi], s);
    }
  }
  if (tx == 0) {
#pragma unroll
    for (int mi = 0; mi < 4; ++mi) {
      const int m = ty * 4 + mi;
      const size_t pidx = (size_t)b * NP + m0 + m;
      const float msk = mask[pidx];
      const float2 pv = *(const float2*)&p_in[pidx * 2];
      if constexpr (!CLS) {
        const float ox = (pr0[mi] + b3[0]) * msk;
        const float oy = (pr1[mi] + b3[1]) * msk;
        out0[pidx * 2 + 0] = pv.x + ox * 4.0f;
        out0[pidx * 2 + 1] = pv.y + oy * 4.0f;
      } else {
        out0[pidx * 2 + 0] = pv.x * 4.0f;
        out0[pidx * 2 + 1] = pv.y * 4.0f;
        out0[(size_t)2 * NB * NP + pidx] = (pr0[mi] + b3[0]) * msk;
      }
    }
  }
}

extern "C" void kernel_launch(void* const* d_in, const int* in_sizes, int n_in,
                              void* d_out, int out_size, void* d_ws,
                              size_t ws_size, hipStream_t stream) {
  const float* image = (const float*)d_in[0];
  const float* pred  = (const float*)d_in[1];
  const float* mask  = (const float*)d_in[2];
  const float* bw    = (const float*)d_in[3];
  const float* bb    = (const float*)d_in[4];
  const float* oW1   = (const float*)d_in[5];
  const float* ob1   = (const float*)d_in[6];
  const float* oW2   = (const float*)d_in[7];
  const float* ob2   = (const float*)d_in[8];
  const float* oW3   = (const float*)d_in[9];
  const float* ob3   = (const float*)d_in[10];
  const float* cW1   = (const float*)d_in[11];
  const float* cb1   = (const float*)d_in[12];
  const float* cW2   = (const float*)d_in[13];
  const float* cb2   = (const float*)d_in[14];
  const float* cW3   = (const float*)d_in[15];
  const float* cb3   = (const float*)d_in[16];
  float* out = (float*)d_out;

  char* ws = (char*)d_ws;
  __hip_bfloat16* feat = (__hip_bfloat16*)ws;
  const size_t featB = (size_t)NB * FH * FW * NC * 2;  // 50.3 MB
  float* pyA  = (float*)(ws + featB);
  float* pyB  = pyA + (size_t)NB * NP * 2;
  float* mins = pyB + (size_t)NB * NP * 2;
  float* wt1  = mins + 16;                       // 4 x [195][256] stride
  float* wt2  = wt1 + (size_t)4 * 195 * 256;     // 4 x [256][256]

  conv_kernel<<<dim3(NB * 16384 / 64), 256, 0, stream>>>(image, bw, bb, feat);

  for (int i = 0; i < 3; ++i) {
    transpose_kernel<<<dim3(194), 256, 0, stream>>>(
        oW1 + (size_t)i * 256 * 194, wt1 + (size_t)i * 195 * 256, 194);
    transpose_kernel<<<dim3(256), 256, 0, stream>>>(
        oW2 + (size_t)i * 65536, wt2 + (size_t)i * 65536, 256);
  }
  transpose_kernel<<<dim3(195), 256, 0, stream>>>(cW1, wt1 + (size_t)3 * 195 * 256, 195);
  transpose_kernel<<<dim3(256), 256, 0, stream>>>(cW2, wt2 + (size_t)3 * 65536, 256);

  const float* cur = pred;
  float* nxt = pyA;
  for (int i = 0; i < 3; ++i) {
    mins_kernel<<<dim3(NB), 256, 0, stream>>>(cur, mask, mins);
    mlp_kernel<false><<<dim3(NB * NP / 64), 256, 0, stream>>>(
        feat, cur, mask, mins,
        wt1 + (size_t)i * 195 * 256, ob1 + (size_t)i * NSTATE,
        wt2 + (size_t)i * 65536, ob2 + (size_t)i * NSTATE,
        oW3 + (size_t)i * 2 * NSTATE, ob3 + (size_t)i * 2, nxt);
    cur = nxt;
    nxt = (nxt == pyA) ? pyB : pyA;
  }
  mlp_kernel<true><<<dim3(NB * NP / 64), 256, 0, stream>>>(
      feat, cur, mask, nullptr, wt1 + (size_t)3 * 195 * 256, cb1,
      wt2 + (size_t)3 * 65536, cb2, cW3, cb3, out);
}

// Round 3
// 409.265 us; speedup vs baseline: 4.2926x; 2.6820x over previous
//
#include <hip/hip_runtime.h>
#include <hip/hip_bf16.h>

#define NB 8
#define NP 8192
#define IMH 512
#define IMW 512
#define NC 192
#define FH 128
#define FW 128
#define NSTATE 256

#define P1 232   // bf16 K-pitch for X / W1b (K padded to 224); 116 dw, bank-balanced
#define P2 264   // bf16 K-pitch for H1 / W2b (K=256); 132 dw, bank-balanced
#define K1PAD 224

typedef __attribute__((ext_vector_type(8))) unsigned short ush8;
typedef __attribute__((ext_vector_type(8))) short short8v;
typedef __attribute__((ext_vector_type(4))) float f32x4;

__device__ __forceinline__ float bf2f(unsigned short u) {
  return __uint_as_float(((unsigned)u) << 16);
}

// ---------------- conv 4x4 stride4 -> feat layout [g][b][pix][48] bf16 ----
__global__ __launch_bounds__(256) void conv_kernel(
    const float* __restrict__ img, const float* __restrict__ bw,
    const float* __restrict__ bb, __hip_bfloat16* __restrict__ feat) {
  __shared__ __hip_bfloat16 ols[4 * 64 * 48];

  const int tid = threadIdx.x;
  const int pix = tid & 63;
  const int g = tid >> 6;
  const int p0 = blockIdx.x * 64;
  const int p = p0 + pix;
  const int b = p >> 14;
  const int yy = (p >> 7) & 127;
  const int xx = p & 127;

  float xin[48];
#pragma unroll
  for (int ci = 0; ci < 3; ++ci) {
#pragma unroll
    for (int ky = 0; ky < 4; ++ky) {
      float4 v = *(const float4*)(img + (((size_t)b * 3 + ci) * IMH +
                                         (yy * 4 + ky)) * IMW + xx * 4);
      xin[ci * 16 + ky * 4 + 0] = v.x;
      xin[ci * 16 + ky * 4 + 1] = v.y;
      xin[ci * 16 + ky * 4 + 2] = v.z;
      xin[ci * 16 + ky * 4 + 3] = v.w;
    }
  }

  const int gu = __builtin_amdgcn_readfirstlane(g);
  for (int cc4 = 0; cc4 < 12; ++cc4) {
    float a[4];
#pragma unroll
    for (int i = 0; i < 4; ++i) a[i] = bb[gu * 48 + cc4 * 4 + i];
#pragma unroll
    for (int k4 = 0; k4 < 12; ++k4) {
#pragma unroll
      for (int i = 0; i < 4; ++i) {
        const float4 wv =
            *(const float4*)(bw + (size_t)(gu * 48 + cc4 * 4 + i) * 48 + k4 * 4);
        a[i] = fmaf(wv.x, xin[k4 * 4 + 0], a[i]);
        a[i] = fmaf(wv.y, xin[k4 * 4 + 1], a[i]);
        a[i] = fmaf(wv.z, xin[k4 * 4 + 2], a[i]);
        a[i] = fmaf(wv.w, xin[k4 * 4 + 3], a[i]);
      }
    }
    __hip_bfloat16 h[4];
#pragma unroll
    for (int i = 0; i < 4; ++i) h[i] = __float2bfloat16(a[i]);
    *(uint2*)&ols[(g * 64 + pix) * 48 + cc4 * 4] = *(const uint2*)h;
  }
  __syncthreads();

  const int bb_ = p0 >> 14;
  const int pixbase = p0 & 16383;
#pragma unroll
  for (int it = 0; it < 6; ++it) {
    const int chunk = it * 256 + tid;
    const int gg = chunk / 384;
    const int off = chunk % 384;
    const ush8 val = ((const ush8*)ols)[chunk];
    __hip_bfloat16* dst =
        feat + ((size_t)(gg * 8 + bb_) * 16384 + pixbase) * 48;
    ((ush8*)dst)[off] = val;
  }
}

// ---------------- weight f32 [256][K] -> bf16 [256][PITCH] zero-padded ----
__global__ void prep_w_kernel(const float* __restrict__ src,
                              __hip_bfloat16* __restrict__ dst, int K,
                              int PITCH) {
  const int idx = blockIdx.x * 256 + threadIdx.x;
  if (idx >= 256 * PITCH) return;
  const int n = idx / PITCH;
  const int k = idx % PITCH;
  const float v = (k < K) ? src[(size_t)n * K + k] : 0.0f;
  dst[idx] = __float2bfloat16(v);
}

// ---------------- per-batch masked min of points ----------------
__global__ void mins_kernel(const float* __restrict__ py,
                            const float* __restrict__ mask,
                            float* __restrict__ mins) {
  int b = blockIdx.x;
  float mx = 1e9f, my = 1e9f;
  for (int n = threadIdx.x; n < NP; n += 256) {
    float m = mask[(size_t)b * NP + n];
    float2 p = *(const float2*)&py[((size_t)b * NP + n) * 2];
    mx = fminf(mx, m > 0.0f ? p.x : 1e9f);
    my = fminf(my, m > 0.0f ? p.y : 1e9f);
  }
#pragma unroll
  for (int o = 32; o > 0; o >>= 1) {
    mx = fminf(mx, __shfl_down(mx, o));
    my = fminf(my, __shfl_down(my, o));
  }
  __shared__ float sx[4], sy[4];
  if ((threadIdx.x & 63) == 0) { sx[threadIdx.x >> 6] = mx; sy[threadIdx.x >> 6] = my; }
  __syncthreads();
  if (threadIdx.x == 0) {
    mx = fminf(fminf(sx[0], sx[1]), fminf(sx[2], sx[3]));
    my = fminf(fminf(sy[0], sy[1]), fminf(sy[2], sy[3]));
    mins[b * 2 + 0] = mx;
    mins[b * 2 + 1] = my;
  }
}

// ---------------- fused gather + MFMA MLP ----------------
// block: 64 points x N=256; 4 waves, wave w owns n in [w*64, w*64+64)
template <bool CLS>
__global__ __launch_bounds__(256, 4) void mlp_kernel(
    const __hip_bfloat16* __restrict__ feat,
    const float* __restrict__ p_in,
    const float* __restrict__ mask,
    const float* __restrict__ mins,
    const __hip_bfloat16* __restrict__ W1b, const float* __restrict__ b1,
    const __hip_bfloat16* __restrict__ W2b, const float* __restrict__ b2,
    const float* __restrict__ W3, const float* __restrict__ b3,
    float* __restrict__ out0) {
  __shared__ __hip_bfloat16 Xls[64 * P2];  // X[64][P1] then H1[64][P2]
  __shared__ float red[4][64][2];

  const int tid = threadIdx.x;
  const int lane = tid & 63;
  const int w = tid >> 6;
  const int cl = lane & 15;
  const int kg = lane >> 4;
  const int b = blockIdx.x >> 7;
  const int m0 = (blockIdx.x & 127) * 64;

  // ---- gather: thread = (point m = tid>>2, 48-ch group j = tid&3) ----
  {
    const int m = tid >> 2;
    const int j = tid & 3;
    const int n = m0 + m;
    const size_t pidx = (size_t)b * NP + n;
    const float msk = mask[pidx];
    const float2 pv = *(const float2*)&p_in[pidx * 2];
    const float px = pv.x, pyv = pv.y;
    const float xs = px * (127.0f / 128.0f);
    const float ys = pyv * (127.0f / 128.0f);
    const float x0f = floorf(xs), y0f = floorf(ys);
    const float fx = xs - x0f, fy = ys - y0f;
    const int x0 = (int)fminf(fmaxf(x0f, 0.0f), 127.0f);
    const int x1 = (int)fminf(fmaxf(x0f + 1.0f, 0.0f), 127.0f);
    const int y0 = (int)fminf(fmaxf(y0f, 0.0f), 127.0f);
    const int y1 = (int)fminf(fmaxf(y0f + 1.0f, 0.0f), 127.0f);
    const float w00 = (1.0f - fy) * (1.0f - fx);
    const float w01 = (1.0f - fy) * fx;
    const float w10 = fy * (1.0f - fx);
    const float w11 = fy * fx;
    const __hip_bfloat16* fb = feat + (size_t)(j * 8 + b) * 16384 * 48;
    const ush8* r00 = (const ush8*)(fb + (size_t)(y0 * FW + x0) * 48);
    const ush8* r01 = (const ush8*)(fb + (size_t)(y0 * FW + x1) * 48);
    const ush8* r10 = (const ush8*)(fb + (size_t)(y1 * FW + x0) * 48);
    const ush8* r11 = (const ush8*)(fb + (size_t)(y1 * FW + x1) * 48);
#pragma unroll
    for (int v = 0; v < 6; ++v) {
      ush8 a0 = r00[v], a1 = r01[v], a2 = r10[v], a3 = r11[v];
      __hip_bfloat16 h[8];
#pragma unroll
      for (int e = 0; e < 8; ++e) {
        float gg = w00 * bf2f(a0[e]) + w01 * bf2f(a1[e]) +
                   w10 * bf2f(a2[e]) + w11 * bf2f(a3[e]);
        h[e] = __float2bfloat16(gg * msk);
      }
      *(ush8*)&Xls[m * P1 + j * 48 + v * 8] = *(const ush8*)h;
    }
    if (j == 0) {
      // extra channels 192..223 (rest zero-padded)
      __hip_bfloat16 ex[32];
#pragma unroll
      for (int i = 0; i < 32; ++i) ex[i] = __float2bfloat16(0.0f);
      if constexpr (!CLS) {
        ex[0] = __float2bfloat16((px - mins[b * 2 + 0]) * msk);
        ex[1] = __float2bfloat16((pyv - mins[b * 2 + 1]) * msk);
      } else {
        ex[0] = __float2bfloat16(px);
        ex[1] = __float2bfloat16(pyv);
        const int npv = (n + NP - 1) & (NP - 1);
        const int nnx = (n + 1) & (NP - 1);
        const float2 pp = *(const float2*)&p_in[((size_t)b * NP + npv) * 2];
        const float2 pn = *(const float2*)&p_in[((size_t)b * NP + nnx) * 2];
        const float v1x = pp.x - px, v1y = pp.y - pyv;
        const float v2x = pn.x - px, v2y = pn.y - pyv;
        const float dot = v1x * v2x + v1y * v2y;
        const float nrm =
            sqrtf(v1x * v1x + v1y * v1y) * sqrtf(v2x * v2x + v2y * v2y);
        const float ca = fminf(fmaxf(dot / (nrm + 1e-8f), -1.0f), 1.0f);
        ex[2] = __float2bfloat16(acosf(ca) * msk);
      }
#pragma unroll
      for (int q = 0; q < 4; ++q)
        *(ush8*)&Xls[m * P1 + 192 + q * 8] = *(const ush8*)&ex[q * 8];
    }
  }
  __syncthreads();

  // ---- GEMM1: H1 = relu(X @ W1^T + b1), MFMA bf16 ----
  f32x4 acc[4][4];
#pragma unroll
  for (int mt = 0; mt < 4; ++mt)
#pragma unroll
    for (int nt = 0; nt < 4; ++nt) acc[mt][nt] = (f32x4){0, 0, 0, 0};

  for (int kc = 0; kc < K1PAD / 32; ++kc) {
    short8v af[4], bfv[4];
#pragma unroll
    for (int mt = 0; mt < 4; ++mt)
      af[mt] = *(const short8v*)&Xls[(mt * 16 + cl) * P1 + kc * 32 + kg * 8];
#pragma unroll
    for (int nt = 0; nt < 4; ++nt)
      bfv[nt] = *(const short8v*)&W1b[(size_t)(w * 64 + nt * 16 + cl) * P1 +
                                      kc * 32 + kg * 8];
#pragma unroll
    for (int mt = 0; mt < 4; ++mt)
#pragma unroll
      for (int nt = 0; nt < 4; ++nt)
        acc[mt][nt] = __builtin_amdgcn_mfma_f32_16x16x32_bf16(
            af[mt], bfv[nt], acc[mt][nt], 0, 0, 0);
  }
  __syncthreads();

  // H1 (bias+relu, bf16) -> Xls as [m][P2]
#pragma unroll
  for (int nt = 0; nt < 4; ++nt) {
    const int n = w * 64 + nt * 16 + cl;
    const float bias = b1[n];
#pragma unroll
    for (int mt = 0; mt < 4; ++mt) {
#pragma unroll
      for (int r = 0; r < 4; ++r) {
        const float v = fmaxf(acc[mt][nt][r] + bias, 0.0f);
        Xls[(mt * 16 + kg * 4 + r) * P2 + n] = __float2bfloat16(v);
      }
    }
  }
  __syncthreads();

  // ---- GEMM2 ----
  f32x4 acc2[4][4];
#pragma unroll
  for (int mt = 0; mt < 4; ++mt)
#pragma unroll
    for (int nt = 0; nt < 4; ++nt) acc2[mt][nt] = (f32x4){0, 0, 0, 0};

  for (int kc = 0; kc < 8; ++kc) {
    short8v af[4], bfv[4];
#pragma unroll
    for (int mt = 0; mt < 4; ++mt)
      af[mt] = *(const short8v*)&Xls[(mt * 16 + cl) * P2 + kc * 32 + kg * 8];
#pragma unroll
    for (int nt = 0; nt < 4; ++nt)
      bfv[nt] = *(const short8v*)&W2b[(size_t)(w * 64 + nt * 16 + cl) * P2 +
                                      kc * 32 + kg * 8];
#pragma unroll
    for (int mt = 0; mt < 4; ++mt)
#pragma unroll
      for (int nt = 0; nt < 4; ++nt)
        acc2[mt][nt] = __builtin_amdgcn_mfma_f32_16x16x32_bf16(
            af[mt], bfv[nt], acc2[mt][nt], 0, 0, 0);
  }

  // ---- GEMM3 (f32) + reduction + epilogue ----
  float pr[4][4][2];
#pragma unroll
  for (int mt = 0; mt < 4; ++mt)
#pragma unroll
    for (int r = 0; r < 4; ++r) { pr[mt][r][0] = 0.0f; pr[mt][r][1] = 0.0f; }

#pragma unroll
  for (int nt = 0; nt < 4; ++nt) {
    const int n = w * 64 + nt * 16 + cl;
    const float bias = b2[n];
    const float w3a = W3[n];
    float w3b = 0.0f;
    if constexpr (!CLS) w3b = W3[256 + n];
#pragma unroll
    for (int mt = 0; mt < 4; ++mt) {
#pragma unroll
      for (int r = 0; r < 4; ++r) {
        const float t = fmaxf(acc2[mt][nt][r] + bias, 0.0f);
        pr[mt][r][0] = fmaf(t, w3a, pr[mt][r][0]);
        if constexpr (!CLS) pr[mt][r][1] = fmaf(t, w3b, pr[mt][r][1]);
      }
    }
  }
#pragma unroll
  for (int s = 1; s < 16; s <<= 1) {
#pragma unroll
    for (int mt = 0; mt < 4; ++mt)
#pragma unroll
      for (int r = 0; r < 4; ++r) {
        pr[mt][r][0] += __shfl_xor(pr[mt][r][0], s);
        if constexpr (!CLS) pr[mt][r][1] += __shfl_xor(pr[mt][r][1], s);
      }
  }
  if constexpr (!CLS) {
    if (cl < 8) {
      const int r = cl >> 1, o = cl & 1;
#pragma unroll
      for (int mt = 0; mt < 4; ++mt)
        red[w][mt * 16 + kg * 4 + r][o] = pr[mt][r][o];
    }
  } else {
    if (cl < 4) {
      const int r = cl;
#pragma unroll
      for (int mt = 0; mt < 4; ++mt)
        red[w][mt * 16 + kg * 4 + r][0] = pr[mt][r][0];
    }
  }
  __syncthreads();

  if constexpr (!CLS) {
    if (tid < 128) {
      const int m = tid >> 1, o = tid & 1;
      const float s = red[0][m][o] + red[1][m][o] + red[2][m][o] + red[3][m][o];
      const size_t pidx = (size_t)b * NP + m0 + m;
      const float msk = mask[pidx];
      const float off = (s + b3[o]) * msk;
      out0[pidx * 2 + o] = p_in[pidx * 2 + o] + off * 4.0f;
    }
  } else {
    if (tid < 64) {
      const int m = tid;
      const float s = red[0][m][0] + red[1][m][0] + red[2][m][0] + red[3][m][0];
      const size_t pidx = (size_t)b * NP + m0 + m;
      const float msk = mask[pidx];
      out0[pidx * 2 + 0] = p_in[pidx * 2 + 0] * 4.0f;
      out0[pidx * 2 + 1] = p_in[pidx * 2 + 1] * 4.0f;
      out0[(size_t)2 * NB * NP + pidx] = (s + b3[0]) * msk;
    }
  }
}

extern "C" void kernel_launch(void* const* d_in, const int* in_sizes, int n_in,
                              void* d_out, int out_size, void* d_ws,
                              size_t ws_size, hipStream_t stream) {
  const float* image = (const float*)d_in[0];
  const float* pred  = (const float*)d_in[1];
  const float* mask  = (const float*)d_in[2];
  const float* bw    = (const float*)d_in[3];
  const float* bb    = (const float*)d_in[4];
  const float* oW1   = (const float*)d_in[5];
  const float* ob1   = (const float*)d_in[6];
  const float* oW2   = (const float*)d_in[7];
  const float* ob2   = (const float*)d_in[8];
  const float* oW3   = (const float*)d_in[9];
  const float* ob3   = (const float*)d_in[10];
  const float* cW1   = (const float*)d_in[11];
  const float* cb1   = (const float*)d_in[12];
  const float* cW2   = (const float*)d_in[13];
  const float* cb2   = (const float*)d_in[14];
  const float* cW3   = (const float*)d_in[15];
  const float* cb3   = (const float*)d_in[16];
  float* out = (float*)d_out;

  char* ws = (char*)d_ws;
  __hip_bfloat16* feat = (__hip_bfloat16*)ws;
  const size_t featB = (size_t)NB * FH * FW * NC * 2;  // 50.3 MB
  float* pyA  = (float*)(ws + featB);
  float* pyB  = pyA + (size_t)NB * NP * 2;
  float* mins = pyB + (size_t)NB * NP * 2;
  __hip_bfloat16* w1b = (__hip_bfloat16*)(mins + 16);     // 4 x [256][P1]
  __hip_bfloat16* w2b = w1b + (size_t)4 * 256 * P1;       // 4 x [256][P2]

  conv_kernel<<<dim3(NB * 16384 / 64), 256, 0, stream>>>(image, bw, bb, feat);

  const int g1 = (256 * P1 + 255) / 256;
  const int g2 = (256 * P2 + 255) / 256;
  for (int i = 0; i < 3; ++i) {
    prep_w_kernel<<<dim3(g1), 256, 0, stream>>>(
        oW1 + (size_t)i * 256 * 194, w1b + (size_t)i * 256 * P1, 194, P1);
    prep_w_kernel<<<dim3(g2), 256, 0, stream>>>(
        oW2 + (size_t)i * 65536, w2b + (size_t)i * 256 * P2, 256, P2);
  }
  prep_w_kernel<<<dim3(g1), 256, 0, stream>>>(cW1, w1b + (size_t)3 * 256 * P1,
                                              195, P1);
  prep_w_kernel<<<dim3(g2), 256, 0, stream>>>(cW2, w2b + (size_t)3 * 256 * P2,
                                              256, P2);

  const float* cur = pred;
  float* nxt = pyA;
  for (int i = 0; i < 3; ++i) {
    mins_kernel<<<dim3(NB), 256, 0, stream>>>(cur, mask, mins);
    mlp_kernel<false><<<dim3(NB * NP / 64), 256, 0, stream>>>(
        feat, cur, mask, mins,
        w1b + (size_t)i * 256 * P1, ob1 + (size_t)i * NSTATE,
        w2b + (size_t)i * 256 * P2, ob2 + (size_t)i * NSTATE,
        oW3 + (size_t)i * 2 * NSTATE, ob3 + (size_t)i * 2, nxt);
    cur = nxt;
    nxt = (nxt == pyA) ? pyB : pyA;
  }
  mlp_kernel<true><<<dim3(NB * NP / 64), 256, 0, stream>>>(
      feat, cur, mask, nullptr, w1b + (size_t)3 * 256 * P1, cb1,
      w2b + (size_t)3 * 256 * P2, cb2, cW3, cb3, out);
}

// Round 4
// 316.314 us; speedup vs baseline: 5.5540x; 1.2939x over previous
//
#include <hip/hip_runtime.h>
#include <hip/hip_bf16.h>

#define NB 8
#define NP 8192
#define IMH 512
#define IMW 512
#define NC 192
#define FH 128
#define FW 128
#define NSTATE 256

#define P1 232   // bf16 K-pitch for X / W1b (K padded to 224); 116 dw, bank-balanced
#define P2 264   // bf16 K-pitch for H1 / W2b (K=256); 132 dw, bank-balanced
#define K1PAD 224
#define CPITCH 72  // conv im2col LDS pitch (bf16): 144 B -> conflict-free b128

typedef __attribute__((ext_vector_type(8))) unsigned short ush8;
typedef __attribute__((ext_vector_type(8))) short short8v;
typedef __attribute__((ext_vector_type(4))) float f32x4;

__device__ __forceinline__ float bf2f(unsigned short u) {
  return __uint_as_float(((unsigned)u) << 16);
}

// ---------------- conv as MFMA GEMM: M=pix, N=192, K=48 ----------------
// block = 64 pixels (half a feature row), 4 waves each own 48 channels.
__global__ __launch_bounds__(256) void conv_kernel(
    const float* __restrict__ img, const __hip_bfloat16* __restrict__ wcb,
    const float* __restrict__ bb, __hip_bfloat16* __restrict__ feat) {
  __shared__ __hip_bfloat16 Xim[64 * CPITCH];  // 9 KB

  const int tid = threadIdx.x;
  const int lane = tid & 63;
  const int w = tid >> 6;
  const int cl = lane & 15;
  const int kg = lane >> 4;
  const int p0 = blockIdx.x * 64;
  const int b = p0 >> 14;
  const int y = (p0 >> 7) & 127;
  const int xh = (p0 >> 6) & 1;

  // zero-pad k in [48,64)
  {
    const int pix = tid & 63;
    const int q = tid >> 6;
    *(uint2*)&Xim[pix * CPITCH + 48 + q * 4] = (uint2){0u, 0u};
  }

  // im2col staging: 12 input rows of 256 f32 -> Xim[pix][ci*16+ky*4+kx] bf16
#pragma unroll
  for (int it = 0; it < 3; ++it) {
    const int idx = it * 256 + tid;  // 0..767
    const int row = idx >> 6;        // ci*4+ky
    const int c = idx & 63;          // local pixel
    const int ci = row >> 2, ky = row & 3;
    const float4 v = *(const float4*)(img + (((size_t)b * 3 + ci) * IMH +
                                             (y * 4 + ky)) * IMW + xh * 256 + c * 4);
    __hip_bfloat16 h[4];
    h[0] = __float2bfloat16(v.x);
    h[1] = __float2bfloat16(v.y);
    h[2] = __float2bfloat16(v.z);
    h[3] = __float2bfloat16(v.w);
    *(uint2*)&Xim[c * CPITCH + ci * 16 + ky * 4] = *(const uint2*)h;
  }
  __syncthreads();

  // MFMA: 4 m-tiles x 3 n-tiles x 2 k-chunks per wave
  f32x4 acc[4][3];
#pragma unroll
  for (int mt = 0; mt < 4; ++mt)
#pragma unroll
    for (int nt = 0; nt < 3; ++nt) acc[mt][nt] = (f32x4){0, 0, 0, 0};

#pragma unroll
  for (int kc = 0; kc < 2; ++kc) {
    short8v af[4], bfv[3];
#pragma unroll
    for (int mt = 0; mt < 4; ++mt)
      af[mt] = *(const short8v*)&Xim[(mt * 16 + cl) * CPITCH + kc * 32 + kg * 8];
#pragma unroll
    for (int nt = 0; nt < 3; ++nt)
      bfv[nt] = *(const short8v*)&wcb[(size_t)(w * 48 + nt * 16 + cl) * 64 +
                                      kc * 32 + kg * 8];
#pragma unroll
    for (int mt = 0; mt < 4; ++mt)
#pragma unroll
      for (int nt = 0; nt < 3; ++nt)
        acc[mt][nt] = __builtin_amdgcn_mfma_f32_16x16x32_bf16(
            af[mt], bfv[nt], acc[mt][nt], 0, 0, 0);
  }

  // epilogue: bias + bf16, direct stores (L2 merges 32B segments)
  const int pixbase = p0 & 16383;
#pragma unroll
  for (int nt = 0; nt < 3; ++nt) {
    const float bias = bb[w * 48 + nt * 16 + cl];
#pragma unroll
    for (int mt = 0; mt < 4; ++mt) {
#pragma unroll
      for (int r = 0; r < 4; ++r) {
        feat[((size_t)(w * 8 + b) * 16384 + pixbase + mt * 16 + kg * 4 + r) * 48 +
             nt * 16 + cl] = __float2bfloat16(acc[mt][nt][r] + bias);
      }
    }
  }
}

// ---------------- fused weight prep: all bf16 weight buffers in 1 launch ----
__global__ void prep_all_kernel(
    const float* __restrict__ oW1, const float* __restrict__ cW1,
    const float* __restrict__ oW2, const float* __restrict__ cW2,
    const float* __restrict__ bw, __hip_bfloat16* __restrict__ w1b,
    __hip_bfloat16* __restrict__ w2b, __hip_bfloat16* __restrict__ wcb) {
  const int idx = blockIdx.x * 256 + threadIdx.x;
  const int region = blockIdx.y;
  if (region == 0) {
    if (idx >= 4 * 256 * P1) return;
    const int L = idx / (256 * P1);
    const int rem = idx - L * (256 * P1);
    const int n = rem / P1;
    const int k = rem - n * P1;
    const float* src = (L < 3) ? (oW1 + (size_t)L * 256 * 194) : cW1;
    const int K = (L < 3) ? 194 : 195;
    w1b[idx] = __float2bfloat16((k < K) ? src[(size_t)n * K + k] : 0.0f);
  } else if (region == 1) {
    if (idx >= 4 * 256 * P2) return;
    const int L = idx / (256 * P2);
    const int rem = idx - L * (256 * P2);
    const int n = rem / P2;
    const int k = rem - n * P2;
    const float* src = (L < 3) ? (oW2 + (size_t)L * 65536) : cW2;
    w2b[idx] = __float2bfloat16((k < 256) ? src[(size_t)n * 256 + k] : 0.0f);
  } else {
    if (idx >= 192 * 64) return;
    const int n = idx >> 6;
    const int k = idx & 63;
    wcb[idx] = __float2bfloat16((k < 48) ? bw[(size_t)n * 48 + k] : 0.0f);
  }
}

// ---------------- per-batch masked min of points ----------------
__global__ void mins_kernel(const float* __restrict__ py,
                            const float* __restrict__ mask,
                            float* __restrict__ mins) {
  int b = blockIdx.x;
  float mx = 1e9f, my = 1e9f;
  for (int n = threadIdx.x; n < NP; n += 256) {
    float m = mask[(size_t)b * NP + n];
    float2 p = *(const float2*)&py[((size_t)b * NP + n) * 2];
    mx = fminf(mx, m > 0.0f ? p.x : 1e9f);
    my = fminf(my, m > 0.0f ? p.y : 1e9f);
  }
#pragma unroll
  for (int o = 32; o > 0; o >>= 1) {
    mx = fminf(mx, __shfl_down(mx, o));
    my = fminf(my, __shfl_down(my, o));
  }
  __shared__ float sx[4], sy[4];
  if ((threadIdx.x & 63) == 0) { sx[threadIdx.x >> 6] = mx; sy[threadIdx.x >> 6] = my; }
  __syncthreads();
  if (threadIdx.x == 0) {
    mx = fminf(fminf(sx[0], sx[1]), fminf(sx[2], sx[3]));
    my = fminf(fminf(sy[0], sy[1]), fminf(sy[2], sy[3]));
    mins[b * 2 + 0] = mx;
    mins[b * 2 + 1] = my;
  }
}

// ---------------- fused gather + MFMA MLP ----------------
// block: 64 points x N=256; 4 waves, wave w owns n in [w*64, w*64+64)
template <bool CLS>
__global__ __launch_bounds__(256, 4) void mlp_kernel(
    const __hip_bfloat16* __restrict__ feat,
    const float* __restrict__ p_in,
    const float* __restrict__ mask,
    const float* __restrict__ mins,
    const __hip_bfloat16* __restrict__ W1b, const float* __restrict__ b1,
    const __hip_bfloat16* __restrict__ W2b, const float* __restrict__ b2,
    const float* __restrict__ W3, const float* __restrict__ b3,
    float* __restrict__ out0) {
  __shared__ __hip_bfloat16 Xls[64 * P2];  // X[64][P1] then H1[64][P2]
  __shared__ float red[4][64][2];

  const int tid = threadIdx.x;
  const int lane = tid & 63;
  const int w = tid >> 6;
  const int cl = lane & 15;
  const int kg = lane >> 4;
  const int b = blockIdx.x >> 7;
  const int m0 = (blockIdx.x & 127) * 64;

  // ---- gather: thread = (point m = tid>>2, 48-ch group j = tid&3) ----
  {
    const int m = tid >> 2;
    const int j = tid & 3;
    const int n = m0 + m;
    const size_t pidx = (size_t)b * NP + n;
    const float msk = mask[pidx];
    const float2 pv = *(const float2*)&p_in[pidx * 2];
    const float px = pv.x, pyv = pv.y;
    const float xs = px * (127.0f / 128.0f);
    const float ys = pyv * (127.0f / 128.0f);
    const float x0f = floorf(xs), y0f = floorf(ys);
    const float fx = xs - x0f, fy = ys - y0f;
    const int x0 = (int)fminf(fmaxf(x0f, 0.0f), 127.0f);
    const int x1 = (int)fminf(fmaxf(x0f + 1.0f, 0.0f), 127.0f);
    const int y0 = (int)fminf(fmaxf(y0f, 0.0f), 127.0f);
    const int y1 = (int)fminf(fmaxf(y0f + 1.0f, 0.0f), 127.0f);
    const float w00 = (1.0f - fy) * (1.0f - fx);
    const float w01 = (1.0f - fy) * fx;
    const float w10 = fy * (1.0f - fx);
    const float w11 = fy * fx;
    const __hip_bfloat16* fb = feat + (size_t)(j * 8 + b) * 16384 * 48;
    const ush8* r00 = (const ush8*)(fb + (size_t)(y0 * FW + x0) * 48);
    const ush8* r01 = (const ush8*)(fb + (size_t)(y0 * FW + x1) * 48);
    const ush8* r10 = (const ush8*)(fb + (size_t)(y1 * FW + x0) * 48);
    const ush8* r11 = (const ush8*)(fb + (size_t)(y1 * FW + x1) * 48);
#pragma unroll
    for (int v = 0; v < 6; ++v) {
      ush8 a0 = r00[v], a1 = r01[v], a2 = r10[v], a3 = r11[v];
      __hip_bfloat16 h[8];
#pragma unroll
      for (int e = 0; e < 8; ++e) {
        float gg = w00 * bf2f(a0[e]) + w01 * bf2f(a1[e]) +
                   w10 * bf2f(a2[e]) + w11 * bf2f(a3[e]);
        h[e] = __float2bfloat16(gg * msk);
      }
      *(ush8*)&Xls[m * P1 + j * 48 + v * 8] = *(const ush8*)h;
    }
    if (j == 0) {
      __hip_bfloat16 ex[32];
#pragma unroll
      for (int i = 0; i < 32; ++i) ex[i] = __float2bfloat16(0.0f);
      if constexpr (!CLS) {
        ex[0] = __float2bfloat16((px - mins[b * 2 + 0]) * msk);
        ex[1] = __float2bfloat16((pyv - mins[b * 2 + 1]) * msk);
      } else {
        ex[0] = __float2bfloat16(px);
        ex[1] = __float2bfloat16(pyv);
        const int npv = (n + NP - 1) & (NP - 1);
        const int nnx = (n + 1) & (NP - 1);
        const float2 pp = *(const float2*)&p_in[((size_t)b * NP + npv) * 2];
        const float2 pn = *(const float2*)&p_in[((size_t)b * NP + nnx) * 2];
        const float v1x = pp.x - px, v1y = pp.y - pyv;
        const float v2x = pn.x - px, v2y = pn.y - pyv;
        const float dot = v1x * v2x + v1y * v2y;
        const float nrm =
            sqrtf(v1x * v1x + v1y * v1y) * sqrtf(v2x * v2x + v2y * v2y);
        const float ca = fminf(fmaxf(dot / (nrm + 1e-8f), -1.0f), 1.0f);
        ex[2] = __float2bfloat16(acosf(ca) * msk);
      }
#pragma unroll
      for (int q = 0; q < 4; ++q)
        *(ush8*)&Xls[m * P1 + 192 + q * 8] = *(const ush8*)&ex[q * 8];
    }
  }
  __syncthreads();

  // ---- GEMM1: H1 = relu(X @ W1^T + b1), MFMA bf16 ----
  f32x4 acc[4][4];
#pragma unroll
  for (int mt = 0; mt < 4; ++mt)
#pragma unroll
    for (int nt = 0; nt < 4; ++nt) acc[mt][nt] = (f32x4){0, 0, 0, 0};

  for (int kc = 0; kc < K1PAD / 32; ++kc) {
    short8v af[4], bfv[4];
#pragma unroll
    for (int mt = 0; mt < 4; ++mt)
      af[mt] = *(const short8v*)&Xls[(mt * 16 + cl) * P1 + kc * 32 + kg * 8];
#pragma unroll
    for (int nt = 0; nt < 4; ++nt)
      bfv[nt] = *(const short8v*)&W1b[(size_t)(w * 64 + nt * 16 + cl) * P1 +
                                      kc * 32 + kg * 8];
#pragma unroll
    for (int mt = 0; mt < 4; ++mt)
#pragma unroll
      for (int nt = 0; nt < 4; ++nt)
        acc[mt][nt] = __builtin_amdgcn_mfma_f32_16x16x32_bf16(
            af[mt], bfv[nt], acc[mt][nt], 0, 0, 0);
  }
  __syncthreads();

  // H1 (bias+relu, bf16) -> Xls as [m][P2]
#pragma unroll
  for (int nt = 0; nt < 4; ++nt) {
    const int n = w * 64 + nt * 16 + cl;
    const float bias = b1[n];
#pragma unroll
    for (int mt = 0; mt < 4; ++mt) {
#pragma unroll
      for (int r = 0; r < 4; ++r) {
        const float v = fmaxf(acc[mt][nt][r] + bias, 0.0f);
        Xls[(mt * 16 + kg * 4 + r) * P2 + n] = __float2bfloat16(v);
      }
    }
  }
  __syncthreads();

  // ---- GEMM2 ----
  f32x4 acc2[4][4];
#pragma unroll
  for (int mt = 0; mt < 4; ++mt)
#pragma unroll
    for (int nt = 0; nt < 4; ++nt) acc2[mt][nt] = (f32x4){0, 0, 0, 0};

  for (int kc = 0; kc < 8; ++kc) {
    short8v af[4], bfv[4];
#pragma unroll
    for (int mt = 0; mt < 4; ++mt)
      af[mt] = *(const short8v*)&Xls[(mt * 16 + cl) * P2 + kc * 32 + kg * 8];
#pragma unroll
    for (int nt = 0; nt < 4; ++nt)
      bfv[nt] = *(const short8v*)&W2b[(size_t)(w * 64 + nt * 16 + cl) * P2 +
                                      kc * 32 + kg * 8];
#pragma unroll
    for (int mt = 0; mt < 4; ++mt)
#pragma unroll
      for (int nt = 0; nt < 4; ++nt)
        acc2[mt][nt] = __builtin_amdgcn_mfma_f32_16x16x32_bf16(
            af[mt], bfv[nt], acc2[mt][nt], 0, 0, 0);
  }

  // ---- GEMM3 (f32) + reduction + epilogue ----
  float pr[4][4][2];
#pragma unroll
  for (int mt = 0; mt < 4; ++mt)
#pragma unroll
    for (int r = 0; r < 4; ++r) { pr[mt][r][0] = 0.0f; pr[mt][r][1] = 0.0f; }

#pragma unroll
  for (int nt = 0; nt < 4; ++nt) {
    const int n = w * 64 + nt * 16 + cl;
    const float bias = b2[n];
    const float w3a = W3[n];
    float w3b = 0.0f;
    if constexpr (!CLS) w3b = W3[256 + n];
#pragma unroll
    for (int mt = 0; mt < 4; ++mt) {
#pragma unroll
      for (int r = 0; r < 4; ++r) {
        const float t = fmaxf(acc2[mt][nt][r] + bias, 0.0f);
        pr[mt][r][0] = fmaf(t, w3a, pr[mt][r][0]);
        if constexpr (!CLS) pr[mt][r][1] = fmaf(t, w3b, pr[mt][r][1]);
      }
    }
  }
#pragma unroll
  for (int s = 1; s < 16; s <<= 1) {
#pragma unroll
    for (int mt = 0; mt < 4; ++mt)
#pragma unroll
      for (int r = 0; r < 4; ++r) {
        pr[mt][r][0] += __shfl_xor(pr[mt][r][0], s);
        if constexpr (!CLS) pr[mt][r][1] += __shfl_xor(pr[mt][r][1], s);
      }
  }
  if constexpr (!CLS) {
    if (cl < 8) {
      const int r = cl >> 1, o = cl & 1;
#pragma unroll
      for (int mt = 0; mt < 4; ++mt)
        red[w][mt * 16 + kg * 4 + r][o] = pr[mt][r][o];
    }
  } else {
    if (cl < 4) {
      const int r = cl;
#pragma unroll
      for (int mt = 0; mt < 4; ++mt)
        red[w][mt * 16 + kg * 4 + r][0] = pr[mt][r][0];
    }
  }
  __syncthreads();

  if constexpr (!CLS) {
    if (tid < 128) {
      const int m = tid >> 1, o = tid & 1;
      const float s = red[0][m][o] + red[1][m][o] + red[2][m][o] + red[3][m][o];
      const size_t pidx = (size_t)b * NP + m0 + m;
      const float msk = mask[pidx];
      const float off = (s + b3[o]) * msk;
      out0[pidx * 2 + o] = p_in[pidx * 2 + o] + off * 4.0f;
    }
  } else {
    if (tid < 64) {
      const int m = tid;
      const float s = red[0][m][0] + red[1][m][0] + red[2][m][0] + red[3][m][0];
      const size_t pidx = (size_t)b * NP + m0 + m;
      const float msk = mask[pidx];
      out0[pidx * 2 + 0] = p_in[pidx * 2 + 0] * 4.0f;
      out0[pidx * 2 + 1] = p_in[pidx * 2 + 1] * 4.0f;
      out0[(size_t)2 * NB * NP + pidx] = (s + b3[0]) * msk;
    }
  }
}

extern "C" void kernel_launch(void* const* d_in, const int* in_sizes, int n_in,
                              void* d_out, int out_size, void* d_ws,
                              size_t ws_size, hipStream_t stream) {
  const float* image = (const float*)d_in[0];
  const float* pred  = (const float*)d_in[1];
  const float* mask  = (const float*)d_in[2];
  const float* bw    = (const float*)d_in[3];
  const float* bb    = (const float*)d_in[4];
  const float* oW1   = (const float*)d_in[5];
  const float* ob1   = (const float*)d_in[6];
  const float* oW2   = (const float*)d_in[7];
  const float* ob2   = (const float*)d_in[8];
  const float* oW3   = (const float*)d_in[9];
  const float* ob3   = (const float*)d_in[10];
  const float* cW1   = (const float*)d_in[11];
  const float* cb1   = (const float*)d_in[12];
  const float* cW2   = (const float*)d_in[13];
  const float* cb2   = (const float*)d_in[14];
  const float* cW3   = (const float*)d_in[15];
  const float* cb3   = (const float*)d_in[16];
  float* out = (float*)d_out;

  char* ws = (char*)d_ws;
  __hip_bfloat16* feat = (__hip_bfloat16*)ws;
  const size_t featB = (size_t)NB * FH * FW * NC * 2;  // 50.3 MB
  float* pyA  = (float*)(ws + featB);
  float* pyB  = pyA + (size_t)NB * NP * 2;
  float* mins = pyB + (size_t)NB * NP * 2;
  __hip_bfloat16* w1b = (__hip_bfloat16*)(mins + 16);     // 4 x [256][P1]
  __hip_bfloat16* w2b = w1b + (size_t)4 * 256 * P1;       // 4 x [256][P2]
  __hip_bfloat16* wcb = w2b + (size_t)4 * 256 * P2;       // [192][64]

  prep_all_kernel<<<dim3(1056, 3), 256, 0, stream>>>(oW1, cW1, oW2, cW2, bw,
                                                     w1b, w2b, wcb);
  conv_kernel<<<dim3(NB * 16384 / 64), 256, 0, stream>>>(image, wcb, bb, feat);

  const float* cur = pred;
  float* nxt = pyA;
  for (int i = 0; i < 3; ++i) {
    mins_kernel<<<dim3(NB), 256, 0, stream>>>(cur, mask, mins);
    mlp_kernel<false><<<dim3(NB * NP / 64), 256, 0, stream>>>(
        feat, cur, mask, mins,
        w1b + (size_t)i * 256 * P1, ob1 + (size_t)i * NSTATE,
        w2b + (size_t)i * 256 * P2, ob2 + (size_t)i * NSTATE,
        oW3 + (size_t)i * 2 * NSTATE, ob3 + (size_t)i * 2, nxt);
    cur = nxt;
    nxt = (nxt == pyA) ? pyB : pyA;
  }
  mlp_kernel<true><<<dim3(NB * NP / 64), 256, 0, stream>>>(
      feat, cur, mask, nullptr, w1b + (size_t)3 * 256 * P1, cb1,
      w2b + (size_t)3 * 256 * P2, cb2, cW3, cb3, out);
}